// Round 1
// baseline (85.526 us; speedup 1.0000x reference)
//
#include <hip/hip_runtime.h>

// ContrastiveCosineLoss: mean over i<j of (cos_full(i,j) - cos_red(i,j))^2
// Fused as ONE GEMM: A_i = [fn_i, rn_i], B_j = [fn_j, -rn_j] (bf16, K=1152),
// diff_ij = dot(A_i, B_j); epilogue accumulates d^2 over upper triangle.

#define NROWS 2048
#define KFULL 1024
#define KRED  128
#define KTOT  1152
#define BK    64
#define BM    64
#define NT    (KTOT / BK)            // 18 K-tiles
#define NEG_T (KFULL / BK)           // tiles >= 16 are the (negated) reduced block
#define TILES (NROWS / BM)           // 32
#define NBLK  (TILES * (TILES + 1) / 2)  // 528 upper-triangular blocks
#define LDT   72                     // padded LDS row stride (elems) -> 144 B, 2-way max

typedef __attribute__((ext_vector_type(8))) short bf16x8;
typedef __attribute__((ext_vector_type(4))) float f32x4;

__device__ inline unsigned short f2bf(float f) {
  unsigned int u = __float_as_uint(f);
  u += 0x7FFFu + ((u >> 16) & 1u);   // round-to-nearest-even
  return (unsigned short)(u >> 16);
}

// One block per row: normalize full (1024) and reduced (128) rows, write
// concatenated bf16 row A[r][0:1152].
__global__ __launch_bounds__(256) void norm_kernel(
    const float* __restrict__ red, const float* __restrict__ full,
    unsigned short* __restrict__ A)
{
  const int r = blockIdx.x;
  const int tid = threadIdx.x;
  const int lane = tid & 63;
  const int wv = tid >> 6;
  __shared__ float part[4];

  const float4 v = ((const float4*)(full + (size_t)r * KFULL))[tid];
  float ss = v.x * v.x + v.y * v.y + v.z * v.z + v.w * v.w;
  #pragma unroll
  for (int o = 32; o > 0; o >>= 1) ss += __shfl_down(ss, o, 64);
  if (lane == 0) part[wv] = ss;
  __syncthreads();
  const float inv = 1.0f / fmaxf(sqrtf(part[0] + part[1] + part[2] + part[3]), 1e-8f);

  unsigned short* Ar = A + (size_t)r * KTOT;
  ushort4 w;
  w.x = f2bf(v.x * inv); w.y = f2bf(v.y * inv);
  w.z = f2bf(v.z * inv); w.w = f2bf(v.w * inv);
  *(ushort4*)(Ar + tid * 4) = w;

  float4 v2 = make_float4(0.f, 0.f, 0.f, 0.f);
  if (tid < 32) v2 = ((const float4*)(red + (size_t)r * KRED))[tid];
  float ss2 = v2.x * v2.x + v2.y * v2.y + v2.z * v2.z + v2.w * v2.w;
  #pragma unroll
  for (int o = 32; o > 0; o >>= 1) ss2 += __shfl_down(ss2, o, 64);
  __syncthreads();   // part[] fully consumed above
  if (lane == 0) part[wv] = ss2;
  __syncthreads();
  const float inv2 = 1.0f / fmaxf(sqrtf(part[0] + part[1] + part[2] + part[3]), 1e-8f);
  if (tid < 32) {
    ushort4 w2;
    w2.x = f2bf(v2.x * inv2); w2.y = f2bf(v2.y * inv2);
    w2.z = f2bf(v2.z * inv2); w2.w = f2bf(v2.w * inv2);
    *(ushort4*)(Ar + KFULL + tid * 4) = w2;
  }
}

// 64x64 tile per block, 4 waves (2x2), 2x2 MFMA 16x16x32 frags per wave.
__global__ __launch_bounds__(256) void pair_gemm(
    const unsigned short* __restrict__ A, float* __restrict__ acc_out)
{
  __shared__ __align__(16) unsigned short ldsA[BM * LDT];
  __shared__ __align__(16) unsigned short ldsB[BM * LDT];
  __shared__ float redbuf[4];

  const int tid = threadIdx.x;

  // linear block id -> upper-triangular (bi, bj), bi <= bj
  int rem = blockIdx.x;
  int bi = 0;
  while (rem >= TILES - bi) { rem -= TILES - bi; ++bi; }
  const int bj = bi + rem;

  // staging: thread t loads 16B at (row = t>>3, k8 = (t&7)*8), two row-halves
  const int srow = tid >> 3;
  const int sk8 = (tid & 7) * 8;
  const unsigned short* pA = A + (size_t)(bi * BM + srow) * KTOT + sk8;
  const unsigned short* pB = A + (size_t)(bj * BM + srow) * KTOT + sk8;

  uint4 ra0, ra1, rb0, rb1;
  auto load_tile = [&](int t) {
    const int ko = t * BK;
    ra0 = *(const uint4*)(pA + ko);
    ra1 = *(const uint4*)(pA + ko + 32 * KTOT);
    rb0 = *(const uint4*)(pB + ko);
    rb1 = *(const uint4*)(pB + ko + 32 * KTOT);
    if (t >= NEG_T) {  // reduced block: B = -A (bf16 sign-bit flip)
      rb0.x ^= 0x80008000u; rb0.y ^= 0x80008000u; rb0.z ^= 0x80008000u; rb0.w ^= 0x80008000u;
      rb1.x ^= 0x80008000u; rb1.y ^= 0x80008000u; rb1.z ^= 0x80008000u; rb1.w ^= 0x80008000u;
    }
  };
  load_tile(0);

  const int lane = tid & 63;
  const int wv = tid >> 6;
  const int wr = wv >> 1, wc = wv & 1;
  const int fr = lane & 15;         // frag row (A) / col (B)
  const int fk = (lane >> 4) * 8;   // frag k-offset within 32

  f32x4 acc[2][2];
  #pragma unroll
  for (int m = 0; m < 2; ++m)
    #pragma unroll
    for (int n = 0; n < 2; ++n)
      acc[m][n] = (f32x4){0.f, 0.f, 0.f, 0.f};

  for (int t = 0; t < NT; ++t) {
    __syncthreads();  // previous tile's ds_reads complete
    *(uint4*)&ldsA[srow * LDT + sk8] = ra0;
    *(uint4*)&ldsA[(srow + 32) * LDT + sk8] = ra1;
    *(uint4*)&ldsB[srow * LDT + sk8] = rb0;
    *(uint4*)&ldsB[(srow + 32) * LDT + sk8] = rb1;
    __syncthreads();

    if (t + 1 < NT) load_tile(t + 1);  // prefetch next tile into regs (hides under MFMA)

    bf16x8 af[2][2], bf[2][2];
    #pragma unroll
    for (int kk = 0; kk < 2; ++kk) {
      #pragma unroll
      for (int m = 0; m < 2; ++m)
        af[m][kk] = *(const bf16x8*)&ldsA[(wr * 32 + m * 16 + fr) * LDT + kk * 32 + fk];
      #pragma unroll
      for (int n = 0; n < 2; ++n)
        bf[n][kk] = *(const bf16x8*)&ldsB[(wc * 32 + n * 16 + fr) * LDT + kk * 32 + fk];
    }
    #pragma unroll
    for (int kk = 0; kk < 2; ++kk)
      #pragma unroll
      for (int m = 0; m < 2; ++m)
        #pragma unroll
        for (int n = 0; n < 2; ++n)
          acc[m][n] = __builtin_amdgcn_mfma_f32_16x16x32_bf16(
              af[m][kk], bf[n][kk], acc[m][n], 0, 0, 0);
  }

  // epilogue: sum d^2 over strict upper triangle (gj > gi)
  float s = 0.f;
  #pragma unroll
  for (int m = 0; m < 2; ++m) {
    const int gi0 = bi * BM + wr * 32 + m * 16 + (lane >> 4) * 4;
    #pragma unroll
    for (int n = 0; n < 2; ++n) {
      const int gj = bj * BM + wc * 32 + n * 16 + fr;
      #pragma unroll
      for (int j = 0; j < 4; ++j) {
        if (gj > gi0 + j) {
          const float d = acc[m][n][j];
          s += d * d;
        }
      }
    }
  }
  #pragma unroll
  for (int o = 32; o > 0; o >>= 1) s += __shfl_down(s, o, 64);
  if (lane == 0) redbuf[wv] = s;
  __syncthreads();
  if (tid == 0) atomicAdd(acc_out, redbuf[0] + redbuf[1] + redbuf[2] + redbuf[3]);
}

__global__ void finalize_kernel(const float* __restrict__ acc, float* __restrict__ out) {
  out[0] = acc[0] * (1.0f / 2096128.0f);  // N*(N-1)/2 pairs
}

extern "C" void kernel_launch(void* const* d_in, const int* in_sizes, int n_in,
                              void* d_out, int out_size, void* d_ws, size_t ws_size,
                              hipStream_t stream)
{
  const float* red  = (const float*)d_in[0];   // (2048, 128) f32
  const float* full = (const float*)d_in[1];   // (2048, 1024) f32
  float* acc = (float*)d_ws;
  unsigned short* A = (unsigned short*)((char*)d_ws + 256);  // 2048*1152 bf16

  hipMemsetAsync(d_ws, 0, 4, stream);
  norm_kernel<<<NROWS, 256, 0, stream>>>(red, full, A);
  pair_gemm<<<NBLK, 256, 0, stream>>>(A, acc);
  finalize_kernel<<<1, 1, 0, stream>>>(acc, (float*)d_out);
}

// Round 2
// 82.504 us; speedup vs baseline: 1.0366x; 1.0366x over previous
//
#include <hip/hip_runtime.h>

// ContrastiveCosineLoss: mean over i<j of (cos_full(i,j) - cos_red(i,j))^2
// Fused as ONE GEMM: A_i = [fn_i, rn_i], B_j = [fn_j, -rn_j] (bf16, K=1152),
// diff_ij = dot(A_i, B_j); epilogue accumulates d^2 over upper triangle.
// 2 dispatches total: norm (also zeroes d_out) + pair_gemm (scaled atomicAdd).

#define NROWS 2048
#define KFULL 1024
#define KRED  128
#define KTOT  1152
#define BK    64
#define BM    64
#define NT    (KTOT / BK)            // 18 K-tiles
#define NEG_T (KFULL / BK)           // tiles >= 16 are the (negated) reduced block
#define TILES (NROWS / BM)           // 32
#define NBLK  (TILES * (TILES + 1) / 2)  // 528 upper-triangular blocks
#define LDT   72                     // padded LDS row stride (elems) -> 144 B
#define INV_PAIRS (1.0f / 2096128.0f)    // 1 / (N*(N-1)/2)

typedef __attribute__((ext_vector_type(8))) short bf16x8;
typedef __attribute__((ext_vector_type(4))) float f32x4;

__device__ inline unsigned short f2bf(float f) {
  unsigned int u = __float_as_uint(f);
  u += 0x7FFFu + ((u >> 16) & 1u);   // round-to-nearest-even
  return (unsigned short)(u >> 16);
}

// One block per row: normalize full (1024) and reduced (128) rows, write
// concatenated bf16 row A[r][0:1152]. Block 0 thread 0 zeroes d_out.
__global__ __launch_bounds__(256) void norm_kernel(
    const float* __restrict__ red, const float* __restrict__ full,
    unsigned short* __restrict__ A, float* __restrict__ out)
{
  const int r = blockIdx.x;
  const int tid = threadIdx.x;
  const int lane = tid & 63;
  const int wv = tid >> 6;
  __shared__ float part[4];

  if (r == 0 && tid == 0) out[0] = 0.0f;   // pair_gemm accumulates into this

  const float4 v = ((const float4*)(full + (size_t)r * KFULL))[tid];
  float ss = v.x * v.x + v.y * v.y + v.z * v.z + v.w * v.w;
  #pragma unroll
  for (int o = 32; o > 0; o >>= 1) ss += __shfl_down(ss, o, 64);
  if (lane == 0) part[wv] = ss;
  __syncthreads();
  const float inv = 1.0f / fmaxf(sqrtf(part[0] + part[1] + part[2] + part[3]), 1e-8f);

  unsigned short* Ar = A + (size_t)r * KTOT;
  ushort4 w;
  w.x = f2bf(v.x * inv); w.y = f2bf(v.y * inv);
  w.z = f2bf(v.z * inv); w.w = f2bf(v.w * inv);
  *(ushort4*)(Ar + tid * 4) = w;

  float4 v2 = make_float4(0.f, 0.f, 0.f, 0.f);
  if (tid < 32) v2 = ((const float4*)(red + (size_t)r * KRED))[tid];
  float ss2 = v2.x * v2.x + v2.y * v2.y + v2.z * v2.z + v2.w * v2.w;
  #pragma unroll
  for (int o = 32; o > 0; o >>= 1) ss2 += __shfl_down(ss2, o, 64);
  __syncthreads();   // part[] fully consumed above
  if (lane == 0) part[wv] = ss2;
  __syncthreads();
  const float inv2 = 1.0f / fmaxf(sqrtf(part[0] + part[1] + part[2] + part[3]), 1e-8f);
  if (tid < 32) {
    ushort4 w2;
    w2.x = f2bf(v2.x * inv2); w2.y = f2bf(v2.y * inv2);
    w2.z = f2bf(v2.z * inv2); w2.w = f2bf(v2.w * inv2);
    *(ushort4*)(Ar + KFULL + tid * 4) = w2;
  }
}

// 64x64 tile per block, 4 waves (2x2), 2x2 MFMA 16x16x32 frags per wave.
// Adds its scaled d^2 partial directly into out[0].
__global__ __launch_bounds__(256) void pair_gemm(
    const unsigned short* __restrict__ A, float* __restrict__ out)
{
  __shared__ __align__(16) unsigned short ldsA[BM * LDT];
  __shared__ __align__(16) unsigned short ldsB[BM * LDT];
  __shared__ float redbuf[4];

  const int tid = threadIdx.x;

  // linear block id -> upper-triangular (bi, bj), bi <= bj
  int rem = blockIdx.x;
  int bi = 0;
  while (rem >= TILES - bi) { rem -= TILES - bi; ++bi; }
  const int bj = bi + rem;

  // staging: thread t loads 16B at (row = t>>3, k8 = (t&7)*8), two row-halves
  const int srow = tid >> 3;
  const int sk8 = (tid & 7) * 8;
  const unsigned short* pA = A + (size_t)(bi * BM + srow) * KTOT + sk8;
  const unsigned short* pB = A + (size_t)(bj * BM + srow) * KTOT + sk8;

  uint4 ra0, ra1, rb0, rb1;
  auto load_tile = [&](int t) {
    const int ko = t * BK;
    ra0 = *(const uint4*)(pA + ko);
    ra1 = *(const uint4*)(pA + ko + 32 * KTOT);
    rb0 = *(const uint4*)(pB + ko);
    rb1 = *(const uint4*)(pB + ko + 32 * KTOT);
    if (t >= NEG_T) {  // reduced block: B = -A (bf16 sign-bit flip)
      rb0.x ^= 0x80008000u; rb0.y ^= 0x80008000u; rb0.z ^= 0x80008000u; rb0.w ^= 0x80008000u;
      rb1.x ^= 0x80008000u; rb1.y ^= 0x80008000u; rb1.z ^= 0x80008000u; rb1.w ^= 0x80008000u;
    }
  };
  load_tile(0);

  const int lane = tid & 63;
  const int wv = tid >> 6;
  const int wr = wv >> 1, wc = wv & 1;
  const int fr = lane & 15;         // frag row (A) / col (B)
  const int fk = (lane >> 4) * 8;   // frag k-offset within 32

  f32x4 acc[2][2];
  #pragma unroll
  for (int m = 0; m < 2; ++m)
    #pragma unroll
    for (int n = 0; n < 2; ++n)
      acc[m][n] = (f32x4){0.f, 0.f, 0.f, 0.f};

  for (int t = 0; t < NT; ++t) {
    __syncthreads();  // previous tile's ds_reads complete
    *(uint4*)&ldsA[srow * LDT + sk8] = ra0;
    *(uint4*)&ldsA[(srow + 32) * LDT + sk8] = ra1;
    *(uint4*)&ldsB[srow * LDT + sk8] = rb0;
    *(uint4*)&ldsB[(srow + 32) * LDT + sk8] = rb1;
    __syncthreads();

    if (t + 1 < NT) load_tile(t + 1);  // prefetch next tile into regs (hides under MFMA)

    bf16x8 af[2][2], bf[2][2];
    #pragma unroll
    for (int kk = 0; kk < 2; ++kk) {
      #pragma unroll
      for (int m = 0; m < 2; ++m)
        af[m][kk] = *(const bf16x8*)&ldsA[(wr * 32 + m * 16 + fr) * LDT + kk * 32 + fk];
      #pragma unroll
      for (int n = 0; n < 2; ++n)
        bf[n][kk] = *(const bf16x8*)&ldsB[(wc * 32 + n * 16 + fr) * LDT + kk * 32 + fk];
    }
    #pragma unroll
    for (int kk = 0; kk < 2; ++kk)
      #pragma unroll
      for (int m = 0; m < 2; ++m)
        #pragma unroll
        for (int n = 0; n < 2; ++n)
          acc[m][n] = __builtin_amdgcn_mfma_f32_16x16x32_bf16(
              af[m][kk], bf[n][kk], acc[m][n], 0, 0, 0);
  }

  // epilogue: sum d^2 over strict upper triangle (gj > gi)
  float s = 0.f;
  #pragma unroll
  for (int m = 0; m < 2; ++m) {
    const int gi0 = bi * BM + wr * 32 + m * 16 + (lane >> 4) * 4;
    #pragma unroll
    for (int n = 0; n < 2; ++n) {
      const int gj = bj * BM + wc * 32 + n * 16 + fr;
      #pragma unroll
      for (int j = 0; j < 4; ++j) {
        if (gj > gi0 + j) {
          const float d = acc[m][n][j];
          s += d * d;
        }
      }
    }
  }
  #pragma unroll
  for (int o = 32; o > 0; o >>= 1) s += __shfl_down(s, o, 64);
  if (lane == 0) redbuf[wv] = s;
  __syncthreads();
  if (tid == 0)
    atomicAdd(out, (redbuf[0] + redbuf[1] + redbuf[2] + redbuf[3]) * INV_PAIRS);
}

extern "C" void kernel_launch(void* const* d_in, const int* in_sizes, int n_in,
                              void* d_out, int out_size, void* d_ws, size_t ws_size,
                              hipStream_t stream)
{
  const float* red  = (const float*)d_in[0];   // (2048, 128) f32
  const float* full = (const float*)d_in[1];   // (2048, 1024) f32
  unsigned short* A = (unsigned short*)d_ws;   // 2048*1152 bf16 = 4.5 MiB

  norm_kernel<<<NROWS, 256, 0, stream>>>(red, full, A, (float*)d_out);
  pair_gemm<<<NBLK, 256, 0, stream>>>(A, (float*)d_out);
}